// Round 17
// baseline (4916.196 us; speedup 1.0000x reference)
//
#include <hip/hip_runtime.h>
#include <hip/hip_bf16.h>

// Bidirectional LSTM, T=512 B=64 D=H=1024, fp32 in/out, bf16 MFMA compute.
// Persistent kernel: 256 WGs x 512 threads (8 waves = 2/SIMD), fwd=WG0..127.
// r13 core (wave flag groups, W bf16 LDS, asm sc1 h burst, ordered vmcnt(4)
// publish, NT out stores) + 2-WAY K-SPLIT TLP: wave pair (wv, wv+4) splits K
// in half (16 h-loads + 16 x-loads + 32 MFMAs each); helper passes partials
// via parity-buffered LDS + LDS flag; owner adds + runs the r13 epilogue.
// Total LLC bytes unchanged; per-wave critical path halved; 2 waves/SIMD
// interleave bursts with compute.

#define TS    512
#define BATCH 64
#define DDIM  1024
#define HDIM  1024
#define KD    2048          // D + H
#define GD    4096          // 4H
#define OUT_HS ((size_t)TS * BATCH * 2 * HDIM)          // 67108864
#define HT_OFF OUT_HS
#define CT_OFF (OUT_HS + (size_t)BATCH * HDIM)

#define WP_BYTES   ((size_t)2 * GD * KD * 2)            // 32 MiB
#define XBF_BYTES  ((size_t)TS * BATCH * DDIM * 2)      // 64 MiB
#define HS_BYTES   ((size_t)2 * 2 * BATCH * HDIM * 2)   // 512 KiB
#define BAR_BYTES  ((size_t)4096)                       // 8 groups x 128 flags
#define WS_A_TOTAL (WP_BYTES + XBF_BYTES + HS_BYTES + BAR_BYTES)
#define WS_B_TOTAL (WP_BYTES + HS_BYTES + BAR_BYTES)

typedef __attribute__((ext_vector_type(8))) short frag8;
typedef __attribute__((ext_vector_type(4))) float f32x4;
typedef unsigned long long u64;

__device__ __forceinline__ ushort f2b(float f) {
  union { float f; unsigned u; } v; v.f = f;
  unsigned r = v.u + 0x7FFFu + ((v.u >> 16) & 1u);   // RNE
  return (ushort)(r >> 16);
}
__device__ __forceinline__ float sigf(float x) { return 1.0f / (1.0f + __expf(-x)); }
__device__ __forceinline__ float tanh_fast(float x) {
  x = fminf(15.0f, fmaxf(-15.0f, x));
  float e = __expf(2.0f * x);
  return (e - 1.0f) / (e + 1.0f);
}

// ---------------- pack kernels ----------------

__global__ void xconv(const float* __restrict__ x, ushort* __restrict__ o) {
  size_t i = ((size_t)blockIdx.x * 256 + threadIdx.x) * 8;
  float4 a = *(const float4*)(x + i);
  float4 b = *(const float4*)(x + i + 4);
  union { ushort s[8]; uint4 v; } r;
  r.s[0] = f2b(a.x); r.s[1] = f2b(a.y); r.s[2] = f2b(a.z); r.s[3] = f2b(a.w);
  r.s[4] = f2b(b.x); r.s[5] = f2b(b.y); r.s[6] = f2b(b.z); r.s[7] = f2b(b.w);
  *(uint4*)(o + i) = r.v;
}

// Build Wpack[dir][p][k] bf16 (k-major), p = wq*32 + gate*8 + jj maps to
// source column n = gate*1024 + wq*8 + jj; rows k<1024 from Wih, else Whh.
__global__ void wpackk(const float* __restrict__ Wih,  const float* __restrict__ Whh,
                       const float* __restrict__ WihR, const float* __restrict__ WhhR,
                       ushort* __restrict__ wp) {
  __shared__ ushort tile[32][36];   // [k_local][p_local]
  int bid = blockIdx.x;
  int kt  = bid & 63;
  int pt  = (bid >> 6) & 127;
  int dir = bid >> 13;
  const float* Wi = dir ? WihR : Wih;
  const float* Wh = dir ? WhhR : Whh;
  int t  = threadIdx.x;
  int kl = t >> 3;
  int g  = (t >> 1) & 3;
  int q  = t & 1;
  int k  = kt * 32 + kl;
  const float* srow = (k < 1024) ? (Wi + (size_t)k * GD) : (Wh + (size_t)(k - 1024) * GD);
  float4 v = *(const float4*)(srow + g * 1024 + pt * 8 + q * 4);
  int pl = g * 8 + q * 4;
  tile[kl][pl + 0] = f2b(v.x); tile[kl][pl + 1] = f2b(v.y);
  tile[kl][pl + 2] = f2b(v.z); tile[kl][pl + 3] = f2b(v.w);
  __syncthreads();
  int po = t >> 3;
  int kc = t & 7;
  ushort* dst = wp + ((size_t)dir * GD + pt * 32 + po) * KD + kt * 32 + kc * 4;
  ushort4 ov;
  ov.x = tile[kc * 4 + 0][po]; ov.y = tile[kc * 4 + 1][po];
  ov.z = tile[kc * 4 + 2][po]; ov.w = tile[kc * 4 + 3][po];
  *(ushort4*)dst = ov;
}

#define MFMA(a, b, c) __builtin_amdgcn_mfma_f32_16x16x32_bf16((a), (b), (c), 0, 0, 0)
#define ALOADU64(p) __hip_atomic_load((p), __ATOMIC_RELAXED, __HIP_MEMORY_SCOPE_AGENT)
#define SB() __builtin_amdgcn_sched_barrier(0)

// ---------------- persistent scan kernel ----------------
// Global flags (zeroed per launch): group g = dir*4 + wv owns bar[g*128+wq],
// value = step generation; published by OWNER waves only after their h(t+1)
// stores drained (ordered vmcnt(4)). Wave pair (wv, wv+4) of WG (dir,wq):
// owner (khalf=0) K in [0,512)+[1024,1536); helper (khalf=1) the other half.
// Helper partial -> pbuf[par][wv] + LDS flag; WAR-safe by flag transitivity
// (helper reaches parity reuse only after poll(t+2) >= owner consumed t).
template <int MODEA>
__global__ __launch_bounds__(512, 1)
void lstm_scan(const ushort* __restrict__ xbf, const float* __restrict__ xf,
               const ushort* __restrict__ wpack,
               const float* __restrict__ bfwd, const float* __restrict__ bbwd,
               ushort* hstate, float* __restrict__ out, unsigned* bar) {
  __shared__ ushort wlds[32 * KD];        // 128 KiB W slice, swizzled
  __shared__ f32x4 pbuf[2][4][2][64];     // 16 KiB helper partials [par][wv][tile][lane]
  __shared__ unsigned hflag[2][4][16];    // [par][wv][0], 512 B

  const int tid  = threadIdx.x;
  const int lane = tid & 63;
  const int w8   = tid >> 6;          // wave 0..7
  const int wv   = w8 & 3;            // row-group: rows [wv*16, wv*16+16)
  const int khalf= w8 >> 2;           // 0 = owner (epilogue), 1 = helper
  const int wg   = blockIdx.x;
  const int dir  = wg >> 7;
  const int wq   = wg & 127;          // owns h-cols [wq*8, wq*8+8)
  unsigned* grpflags = bar + (dir * 4 + wv) * 128;

  // stage W slice into LDS (XOR swizzle: byte ^= (p&7)<<4), 512 threads
  {
    const ushort* src = wpack + ((size_t)dir * GD + wq * 32) * KD;
#pragma unroll
    for (int it = 0; it < 16; ++it) {
      int m  = it * 512 + tid;
      int p  = m >> 8;
      int kc = m & 255;
      uint4 v = *(const uint4*)(src + (size_t)p * KD + kc * 8);
      int off = p * 4096 + ((kc * 16) ^ ((p & 7) << 4));
      *(uint4*)((char*)wlds + off) = v;
    }
  }
  if (tid < 128) ((unsigned*)hflag)[tid] = 0;
  __syncthreads();   // only WG-wide sync; LDS W read-only afterwards

  const int lm   = lane & 15;
  const int jj   = lane & 7;
  const int kg   = lane >> 4;
  const int kb   = kg * 8;            // elements within a 32-k step
  const int kb2  = kb * 2;            // bytes
  const int arow = wv * 16 + lm;
  const int hcol = wq * 8 + jj;
  const int sw   = jj << 4;
  const int b0base = lm * 4096;
  const int b1base = (16 + lm) * 4096;
  const int ksb  = khalf * 16;        // this wave's kstep base (of 32)

  const float* bsrc = dir ? bbwd : bfwd;
  const float bias0 = bsrc[(lm >> 3) * HDIM + hcol];
  const float bias1 = bsrc[(2 + (lm >> 3)) * HDIM + hcol];

  float creg[4] = {0.f, 0.f, 0.f, 0.f};
  float hvv[4];
  f32x4 a0a, a0b, a1a, a1b;

  auto poll = [&](int gen) {
    const unsigned want = (unsigned)gen;
    const u64* f2 = (const u64*)grpflags + lane;
    for (;;) {
      u64 v = ALOADU64(f2);
      if ((unsigned)v >= want && (unsigned)(v >> 32) >= want) break;
      __builtin_amdgcn_s_sleep(1);
    }
    __atomic_signal_fence(__ATOMIC_SEQ_CST);
    asm volatile("" ::: "memory");
  };

  if (MODEA) {
    // ---- x contribution over this wave's 16 ksteps; resets accumulators ----
    auto compute_x = [&](int tt) {
      const int tsrc = dir ? (TS - 1 - tt) : tt;
      a0a = (f32x4){0.f,0.f,0.f,0.f}; a0b = (f32x4){0.f,0.f,0.f,0.f};
      a1a = (f32x4){0.f,0.f,0.f,0.f}; a1b = (f32x4){0.f,0.f,0.f,0.f};
      const ushort* xs = xbf + ((size_t)tsrc * BATCH + arow) * DDIM + ksb * 32 + kb;
#pragma unroll 8
      for (int kk = 0; kk < 16; kk += 2) {
        frag8 a  = *(const frag8*)(xs + kk * 32);
        frag8 a2 = *(const frag8*)(xs + (kk + 1) * 32);
        int ko  = (((ksb + kk) * 64) + kb2) ^ sw;
        int ko2 = (((ksb + kk + 1) * 64) + kb2) ^ sw;
        frag8 b0  = *(const frag8*)((const char*)wlds + (b0base + ko));
        frag8 b1  = *(const frag8*)((const char*)wlds + (b1base + ko));
        frag8 b02 = *(const frag8*)((const char*)wlds + (b0base + ko2));
        frag8 b12 = *(const frag8*)((const char*)wlds + (b1base + ko2));
        a0a = MFMA(a, b0, a0a);  a1a = MFMA(a, b1, a1a);
        a0b = MFMA(a2, b02, a0b); a1b = MFMA(a2, b12, a1b);
      }
    };

    // ---- h contribution over this wave's 16 ksteps (asm sc1 burst) ----
    auto h_part = [&](int t) {
      const ushort* hsrd = hstate + (((size_t)(t & 1) * 2 + dir) * BATCH + arow) * HDIM
                           + ksb * 32 + kb;
      frag8 hf[16];
#pragma unroll
      for (int kk = 0; kk < 16; ++kk)
        asm volatile("global_load_dwordx4 %0, %1, off offset:%2 sc1"
                     : "=v"(hf[kk]) : "v"(hsrd), "i"(kk * 64) : "memory");
      asm volatile("s_waitcnt vmcnt(0)" ::: "memory");
      SB();
#pragma unroll
      for (int kk = 0; kk < 16; kk += 2) {
        int ko  = (2048 + (ksb + kk) * 64 + kb2) ^ sw;
        int ko2 = (2048 + (ksb + kk + 1) * 64 + kb2) ^ sw;
        frag8 b0  = *(const frag8*)((const char*)wlds + (b0base + ko));
        frag8 b1  = *(const frag8*)((const char*)wlds + (b1base + ko));
        frag8 b02 = *(const frag8*)((const char*)wlds + (b0base + ko2));
        frag8 b12 = *(const frag8*)((const char*)wlds + (b1base + ko2));
        a0a = MFMA(hf[kk], b0, a0a);      a1a = MFMA(hf[kk], b1, a1a);
        a0b = MFMA(hf[kk + 1], b02, a0b); a1b = MFMA(hf[kk + 1], b12, a1b);
      }
    };

    compute_x(0);

    for (int t = 0; t < TS; ++t) {
      if (t > 0) h_part(t);
      const int par = t & 1;
      const bool last = (t == TS - 1);

      if (khalf == 1) {
        // -------- helper: hand partial to owner, then advance --------
        pbuf[par][wv][0][lane] = a0a + a0b;
        pbuf[par][wv][1][lane] = a1a + a1b;
        asm volatile("s_waitcnt lgkmcnt(0)" ::: "memory");
        SB();
        if (lane == 0)
          __hip_atomic_store(&hflag[par][wv][0], (unsigned)(t + 1),
                             __ATOMIC_RELAXED, __HIP_MEMORY_SCOPE_WORKGROUP);
        if (last) break;
        compute_x(t + 1);
        poll(t + 1);
      } else {
        // -------- owner: combine, epilogue, publish --------
        f32x4 acc0 = a0a + a0b;
        f32x4 acc1 = a1a + a1b;
        while (__hip_atomic_load(&hflag[par][wv][0], __ATOMIC_RELAXED,
                                 __HIP_MEMORY_SCOPE_WORKGROUP) < (unsigned)(t + 1))
          __builtin_amdgcn_s_sleep(1);
        SB();
        asm volatile("" ::: "memory");
        acc0 += pbuf[par][wv][0][lane];
        acc1 += pbuf[par][wv][1][lane];

        const int tsrc = dir ? (TS - 1 - t) : t;
        ushort* hnext = hstate + ((size_t)(((t + 1) & 1) * 2 + dir) * BATCH) * HDIM;
        const size_t obase = ((size_t)tsrc * BATCH) * (2 * HDIM) + (size_t)dir * HDIM + hcol;
        const bool last_f = (dir == 0) && last;

#pragma unroll
        for (int i = 0; i < 4; ++i) {
          float g0 = acc0[i] + bias0;
          float g1 = acc1[i] + bias1;
          float q0 = __shfl_xor(g0, 8);
          float q1 = __shfl_xor(g1, 8);
          if ((lane & 8) == 0) {
            float cn = sigf(q0) * creg[i] + sigf(g0) * tanh_fast(g1);
            creg[i] = cn;
            hvv[i] = sigf(q1) * tanh_fast(cn);
          }
        }
        // h-state stores FIRST (covered by the vmcnt(4) publish wait)
        if (!last) {
#pragma unroll
          for (int i = 0; i < 4; ++i) {
            if ((lane & 8) == 0) {
              int brow = wv * 16 + (lane >> 4) * 4 + i;
              __hip_atomic_store(hnext + (size_t)brow * HDIM + hcol, f2b(hvv[i]),
                                 __ATOMIC_RELAXED, __HIP_MEMORY_SCOPE_AGENT);
            }
          }
        }
        SB();
        // out stores SECOND (acks drain lazily at the next h-wait)
#pragma unroll
        for (int i = 0; i < 4; ++i) {
          if ((lane & 8) == 0) {
            int brow = wv * 16 + (lane >> 4) * 4 + i;
            __builtin_nontemporal_store(hvv[i], out + obase + (size_t)brow * (2 * HDIM));
          }
        }
        if (last_f) {
#pragma unroll
          for (int i = 0; i < 4; ++i) {
            if ((lane & 8) == 0) {
              int brow = wv * 16 + (lane >> 4) * 4 + i;
              __builtin_nontemporal_store(hvv[i], out + HT_OFF + (size_t)brow * HDIM + hcol);
              __builtin_nontemporal_store(creg[i], out + CT_OFF + (size_t)brow * HDIM + hcol);
            }
          }
        }
        if (last) break;

        asm volatile("s_waitcnt vmcnt(4)" ::: "memory");
        if (lane == 0)
          __hip_atomic_store(grpflags + wq, (unsigned)(t + 1),
                             __ATOMIC_RELAXED, __HIP_MEMORY_SCOPE_AGENT);
        compute_x(t + 1);
        poll(t + 1);
      }
    }
  } else {
    // ---------------- MODEB fallback: r13 path on waves 0..3 ----------------
    if (khalf == 1) return;   // after the only __syncthreads
    auto compute_x_old = [&](int tt) {
      const int tsrc = dir ? (TS - 1 - tt) : tt;
      a0a = (f32x4){0.f,0.f,0.f,0.f}; a0b = (f32x4){0.f,0.f,0.f,0.f};
      a1a = (f32x4){0.f,0.f,0.f,0.f}; a1b = (f32x4){0.f,0.f,0.f,0.f};
      const float* xs = xf + ((size_t)tsrc * BATCH + arow) * DDIM + kb;
#pragma unroll 4
      for (int kk = 0; kk < 32; ++kk) {
        float4 f0 = *(const float4*)(xs + kk * 32);
        float4 f1 = *(const float4*)(xs + kk * 32 + 4);
        union { ushort s[8]; frag8 fr; } ua;
        ua.s[0] = f2b(f0.x); ua.s[1] = f2b(f0.y); ua.s[2] = f2b(f0.z); ua.s[3] = f2b(f0.w);
        ua.s[4] = f2b(f1.x); ua.s[5] = f2b(f1.y); ua.s[6] = f2b(f1.z); ua.s[7] = f2b(f1.w);
        int ko = (kk * 64 + kb2) ^ sw;
        frag8 b0 = *(const frag8*)((const char*)wlds + (b0base + ko));
        frag8 b1 = *(const frag8*)((const char*)wlds + (b1base + ko));
        if (kk & 1) { a0b = MFMA(ua.fr, b0, a0b); a1b = MFMA(ua.fr, b1, a1b); }
        else        { a0a = MFMA(ua.fr, b0, a0a); a1a = MFMA(ua.fr, b1, a1a); }
      }
    };
    auto h_part_old = [&](int t) {
      const ushort* hsrd = hstate + (((size_t)(t & 1) * 2 + dir) * BATCH + arow) * HDIM + kb;
      frag8 hf[32];
#pragma unroll
      for (int kk = 0; kk < 32; ++kk)
        asm volatile("global_load_dwordx4 %0, %1, off offset:%2 sc1"
                     : "=v"(hf[kk]) : "v"(hsrd), "i"(kk * 64) : "memory");
      asm volatile("s_waitcnt vmcnt(0)" ::: "memory");
      SB();
#pragma unroll
      for (int kk = 0; kk < 32; kk += 2) {
        int ko  = (2048 + kk * 64 + kb2) ^ sw;
        int ko2 = (2048 + (kk + 1) * 64 + kb2) ^ sw;
        frag8 b0  = *(const frag8*)((const char*)wlds + (b0base + ko));
        frag8 b1  = *(const frag8*)((const char*)wlds + (b1base + ko));
        frag8 b02 = *(const frag8*)((const char*)wlds + (b0base + ko2));
        frag8 b12 = *(const frag8*)((const char*)wlds + (b1base + ko2));
        a0a = MFMA(hf[kk], b0, a0a);      a1a = MFMA(hf[kk], b1, a1a);
        a0b = MFMA(hf[kk + 1], b02, a0b); a1b = MFMA(hf[kk + 1], b12, a1b);
      }
    };
    compute_x_old(0);
    for (int t = 0; t < TS; ++t) {
      if (t > 0) h_part_old(t);
      const int tsrc = dir ? (TS - 1 - t) : t;
      f32x4 acc0 = a0a + a0b, acc1 = a1a + a1b;
      ushort* hnext = hstate + ((size_t)(((t + 1) & 1) * 2 + dir) * BATCH) * HDIM;
      const size_t obase = ((size_t)tsrc * BATCH) * (2 * HDIM) + (size_t)dir * HDIM + hcol;
      const bool last = (t == TS - 1);
      const bool last_f = (dir == 0) && last;
#pragma unroll
      for (int i = 0; i < 4; ++i) {
        float g0 = acc0[i] + bias0;
        float g1 = acc1[i] + bias1;
        float q0 = __shfl_xor(g0, 8);
        float q1 = __shfl_xor(g1, 8);
        if ((lane & 8) == 0) {
          float cn = sigf(q0) * creg[i] + sigf(g0) * tanh_fast(g1);
          creg[i] = cn;
          float hv = sigf(q1) * tanh_fast(cn);
          int brow = wv * 16 + (lane >> 4) * 4 + i;
          out[obase + (size_t)brow * (2 * HDIM)] = hv;
          if (!last)
            __hip_atomic_store(hnext + (size_t)brow * HDIM + hcol, f2b(hv),
                               __ATOMIC_RELAXED, __HIP_MEMORY_SCOPE_AGENT);
          if (last_f) {
            out[HT_OFF + (size_t)brow * HDIM + hcol] = hv;
            out[CT_OFF + (size_t)brow * HDIM + hcol] = cn;
          }
        }
      }
      if (last) break;
      asm volatile("s_waitcnt vmcnt(0)" ::: "memory");
      if (lane == 0)
        __hip_atomic_store(grpflags + wq, (unsigned)(t + 1),
                           __ATOMIC_RELAXED, __HIP_MEMORY_SCOPE_AGENT);
      compute_x_old(t + 1);
      poll(t + 1);
    }
  }
}

extern "C" void kernel_launch(void* const* d_in, const int* in_sizes, int n_in,
                              void* d_out, int out_size, void* d_ws, size_t ws_size,
                              hipStream_t stream) {
  const float* x    = (const float*)d_in[0];
  const float* Wih  = (const float*)d_in[1];
  const float* Whh  = (const float*)d_in[2];
  const float* b    = (const float*)d_in[3];
  const float* WihR = (const float*)d_in[4];
  const float* WhhR = (const float*)d_in[5];
  const float* bR   = (const float*)d_in[6];
  float* out = (float*)d_out;
  char* ws = (char*)d_ws;

  if (ws_size < WS_B_TOTAL) return;  // cannot run; surfaces as wrong-answer
  const bool modeA = (ws_size >= WS_A_TOTAL);

  ushort* wp  = (ushort*)(ws);
  ushort* xbf = (ushort*)(ws + WP_BYTES);
  size_t hs_off = modeA ? (WP_BYTES + XBF_BYTES) : WP_BYTES;
  ushort* hs = (ushort*)(ws + hs_off);
  unsigned* bar = (unsigned*)(ws + hs_off + HS_BYTES);

  // zero the flag region (flags are monotonic within one launch; reset per launch)
  hipMemsetAsync(ws + hs_off + HS_BYTES, 0, BAR_BYTES, stream);

  // pack weights: 2 dirs * 128 p-tiles * 64 k-tiles
  wpackk<<<dim3(16384), dim3(256), 0, stream>>>(Wih, Whh, WihR, WhhR, wp);

  if (modeA) {
    xconv<<<dim3(16384), dim3(256), 0, stream>>>(x, xbf);  // 16384*256*8 == T*B*D
    lstm_scan<1><<<dim3(256), dim3(512), 0, stream>>>(xbf, x, wp, b, bR, hs, out, bar);
  } else {
    lstm_scan<0><<<dim3(256), dim3(512), 0, stream>>>(nullptr, x, wp, b, bR, hs, out, bar);
  }
}

// Round 18
// 4383.604 us; speedup vs baseline: 1.1215x; 1.1215x over previous
//
#include <hip/hip_runtime.h>
#include <hip/hip_bf16.h>

// Bidirectional LSTM, T=512 B=64 D=H=1024, fp32 in/out, bf16 MFMA compute.
// Persistent kernel: 256 WGs (1/CU), fwd=WG0..127, bwd=WG128..255.
// r13 structure (W bf16 LDS, asm sc1 32-deep h burst, ordered vmcnt(4)
// publish, NT out stores) + AGGREGATE-COUNTER barrier: producers atomicAdd(+1)
// (relaxed agent - no wbl2) on their group's counter; consumers poll ONE
// address (single coalesced request/iter vs 128-flag per-lane polling).

#define TS    512
#define BATCH 64
#define DDIM  1024
#define HDIM  1024
#define KD    2048          // D + H
#define GD    4096          // 4H
#define OUT_HS ((size_t)TS * BATCH * 2 * HDIM)          // 67108864
#define HT_OFF OUT_HS
#define CT_OFF (OUT_HS + (size_t)BATCH * HDIM)

#define WP_BYTES   ((size_t)2 * GD * KD * 2)            // 32 MiB
#define XBF_BYTES  ((size_t)TS * BATCH * DDIM * 2)      // 64 MiB
#define HS_BYTES   ((size_t)2 * 2 * BATCH * HDIM * 2)   // 512 KiB
#define BAR_BYTES  ((size_t)4096)                       // 8 counters, 256B apart
#define WS_A_TOTAL (WP_BYTES + XBF_BYTES + HS_BYTES + BAR_BYTES)
#define WS_B_TOTAL (WP_BYTES + HS_BYTES + BAR_BYTES)

typedef __attribute__((ext_vector_type(8))) short frag8;
typedef __attribute__((ext_vector_type(4))) float f32x4;
typedef unsigned long long u64;

__device__ __forceinline__ ushort f2b(float f) {
  union { float f; unsigned u; } v; v.f = f;
  unsigned r = v.u + 0x7FFFu + ((v.u >> 16) & 1u);   // RNE
  return (ushort)(r >> 16);
}
__device__ __forceinline__ float sigf(float x) { return 1.0f / (1.0f + __expf(-x)); }
__device__ __forceinline__ float tanh_fast(float x) {
  x = fminf(15.0f, fmaxf(-15.0f, x));
  float e = __expf(2.0f * x);
  return (e - 1.0f) / (e + 1.0f);
}

// ---------------- pack kernels ----------------

__global__ void xconv(const float* __restrict__ x, ushort* __restrict__ o) {
  size_t i = ((size_t)blockIdx.x * 256 + threadIdx.x) * 8;
  float4 a = *(const float4*)(x + i);
  float4 b = *(const float4*)(x + i + 4);
  union { ushort s[8]; uint4 v; } r;
  r.s[0] = f2b(a.x); r.s[1] = f2b(a.y); r.s[2] = f2b(a.z); r.s[3] = f2b(a.w);
  r.s[4] = f2b(b.x); r.s[5] = f2b(b.y); r.s[6] = f2b(b.z); r.s[7] = f2b(b.w);
  *(uint4*)(o + i) = r.v;
}

// Build Wpack[dir][p][k] bf16 (k-major), p = wq*32 + gate*8 + jj maps to
// source column n = gate*1024 + wq*8 + jj; rows k<1024 from Wih, else Whh.
__global__ void wpackk(const float* __restrict__ Wih,  const float* __restrict__ Whh,
                       const float* __restrict__ WihR, const float* __restrict__ WhhR,
                       ushort* __restrict__ wp) {
  __shared__ ushort tile[32][36];   // [k_local][p_local]
  int bid = blockIdx.x;
  int kt  = bid & 63;
  int pt  = (bid >> 6) & 127;
  int dir = bid >> 13;
  const float* Wi = dir ? WihR : Wih;
  const float* Wh = dir ? WhhR : Whh;
  int t  = threadIdx.x;
  int kl = t >> 3;
  int g  = (t >> 1) & 3;
  int q  = t & 1;
  int k  = kt * 32 + kl;
  const float* srow = (k < 1024) ? (Wi + (size_t)k * GD) : (Wh + (size_t)(k - 1024) * GD);
  float4 v = *(const float4*)(srow + g * 1024 + pt * 8 + q * 4);
  int pl = g * 8 + q * 4;
  tile[kl][pl + 0] = f2b(v.x); tile[kl][pl + 1] = f2b(v.y);
  tile[kl][pl + 2] = f2b(v.z); tile[kl][pl + 3] = f2b(v.w);
  __syncthreads();
  int po = t >> 3;
  int kc = t & 7;
  ushort* dst = wp + ((size_t)dir * GD + pt * 32 + po) * KD + kt * 32 + kc * 4;
  ushort4 ov;
  ov.x = tile[kc * 4 + 0][po]; ov.y = tile[kc * 4 + 1][po];
  ov.z = tile[kc * 4 + 2][po]; ov.w = tile[kc * 4 + 3][po];
  *(ushort4*)dst = ov;
}

#define MFMA(a, b, c) __builtin_amdgcn_mfma_f32_16x16x32_bf16((a), (b), (c), 0, 0, 0)
#define SB() __builtin_amdgcn_sched_barrier(0)

// ---------------- persistent scan kernel ----------------
// Counter layout in `bar` (zeroed per launch): group g = dir*4 + wv owns the
// counter at bar[g*64] (256B apart -> distinct lines). Each of the group's
// 128 producer waves adds +1 per step AFTER its h-stores drained (vmcnt(4));
// consumers wait until ctr >= 128*(t+1). Monotonic within a launch.
template <int MODEA>
__global__ __launch_bounds__(256, 1)
void lstm_scan(const ushort* __restrict__ xbf, const float* __restrict__ xf,
               const ushort* __restrict__ wpack,
               const float* __restrict__ bfwd, const float* __restrict__ bbwd,
               ushort* hstate, float* __restrict__ out, unsigned* bar) {
  __shared__ ushort wlds[32 * KD];   // 128 KiB: this WG's 32 packed cols x 2048 K, swizzled

  const int tid  = threadIdx.x;
  const int lane = tid & 63;
  const int wv   = tid >> 6;         // wave 0..3 -> rows wv*16..
  const int wg   = blockIdx.x;
  const int dir  = wg >> 7;          // 0 fwd, 1 bwd
  const int wq   = wg & 127;         // owns h-cols [wq*8, wq*8+8)
  unsigned* ctr  = bar + (dir * 4 + wv) * 64;   // this wave's group counter

  // stage W slice into LDS (XOR swizzle: byte ^= (p&7)<<4)
  {
    const ushort* src = wpack + ((size_t)dir * GD + wq * 32) * KD;
#pragma unroll
    for (int it = 0; it < 32; ++it) {
      int m  = it * 256 + tid;
      int p  = m >> 8;
      int kc = m & 255;
      uint4 v = *(const uint4*)(src + (size_t)p * KD + kc * 8);
      int off = p * 4096 + ((kc * 16) ^ ((p & 7) << 4));
      *(uint4*)((char*)wlds + off) = v;
    }
  }
  __syncthreads();   // only sync: W staging complete; LDS read-only afterwards

  const int lm   = lane & 15;
  const int jj   = lane & 7;
  const int kb   = (lane >> 4) * 8;  // A-frag k sub-block (elements)
  const int kb2  = kb * 2;           // bytes
  const int arow = wv * 16 + lm;     // A row this lane reads
  const int hcol = wq * 8 + jj;
  const int sw   = jj << 4;          // == (p&7)<<4 for both tiles
  const int b0base = lm * 4096;
  const int b1base = (16 + lm) * 4096;

  const float* bsrc = dir ? bbwd : bfwd;
  const float bias0 = bsrc[(lm >> 3) * HDIM + hcol];        // gate 0/1 (i,f)
  const float bias1 = bsrc[(2 + (lm >> 3)) * HDIM + hcol];  // gate 2/3 (g,o)

  float creg[4] = {0.f, 0.f, 0.f, 0.f};
  float hvv[4];
  f32x4 a0a, a0b, a1a, a1b;

  // ---- x contribution for timestep tt (k in [0,1024)); resets accumulators ----
  auto compute_x = [&](int tt) {
    const int tsrc = dir ? (TS - 1 - tt) : tt;
    a0a = (f32x4){0.f,0.f,0.f,0.f}; a0b = (f32x4){0.f,0.f,0.f,0.f};
    a1a = (f32x4){0.f,0.f,0.f,0.f}; a1b = (f32x4){0.f,0.f,0.f,0.f};
    if (MODEA) {
      const ushort* xs = xbf + ((size_t)tsrc * BATCH + arow) * DDIM + kb;
#pragma unroll 8
      for (int kk = 0; kk < 32; kk += 2) {
        frag8 a  = *(const frag8*)(xs + kk * 32);
        frag8 a2 = *(const frag8*)(xs + (kk + 1) * 32);
        int ko  = (kk * 64 + kb2) ^ sw;
        int ko2 = ((kk + 1) * 64 + kb2) ^ sw;
        frag8 b0  = *(const frag8*)((const char*)wlds + (b0base + ko));
        frag8 b1  = *(const frag8*)((const char*)wlds + (b1base + ko));
        frag8 b02 = *(const frag8*)((const char*)wlds + (b0base + ko2));
        frag8 b12 = *(const frag8*)((const char*)wlds + (b1base + ko2));
        a0a = MFMA(a, b0, a0a);  a1a = MFMA(a, b1, a1a);
        a0b = MFMA(a2, b02, a0b); a1b = MFMA(a2, b12, a1b);
      }
    } else {
      const float* xs = xf + ((size_t)tsrc * BATCH + arow) * DDIM + kb;
#pragma unroll 4
      for (int kk = 0; kk < 32; ++kk) {
        float4 f0 = *(const float4*)(xs + kk * 32);
        float4 f1 = *(const float4*)(xs + kk * 32 + 4);
        union { ushort s[8]; frag8 fr; } ua;
        ua.s[0] = f2b(f0.x); ua.s[1] = f2b(f0.y); ua.s[2] = f2b(f0.z); ua.s[3] = f2b(f0.w);
        ua.s[4] = f2b(f1.x); ua.s[5] = f2b(f1.y); ua.s[6] = f2b(f1.z); ua.s[7] = f2b(f1.w);
        int ko = (kk * 64 + kb2) ^ sw;
        frag8 b0 = *(const frag8*)((const char*)wlds + (b0base + ko));
        frag8 b1 = *(const frag8*)((const char*)wlds + (b1base + ko));
        if (kk & 1) { a0b = MFMA(ua.fr, b0, a0b); a1b = MFMA(ua.fr, b1, a1b); }
        else        { a0a = MFMA(ua.fr, b0, a0a); a1a = MFMA(ua.fr, b1, a1a); }
      }
    }
  };

  // ---- h contribution for timestep t (k in [1024,2048)) ----
  // Inline-asm FORCED 32-deep sc1 load burst (r8), single vmcnt drain,
  // sched_barrier per rule #18.
  auto h_part = [&](int t) {
    const ushort* hsrd = hstate + (((size_t)(t & 1) * 2 + dir) * BATCH + arow) * HDIM + kb;
    frag8 hf[32];
#pragma unroll
    for (int kk = 0; kk < 32; ++kk)
      asm volatile("global_load_dwordx4 %0, %1, off offset:%2 sc1"
                   : "=v"(hf[kk]) : "v"(hsrd), "i"(kk * 64) : "memory");
    asm volatile("s_waitcnt vmcnt(0)" ::: "memory");
    SB();
#pragma unroll
    for (int kk = 0; kk < 32; kk += 2) {
      int ko  = (2048 + kk * 64 + kb2) ^ sw;
      int ko2 = (2048 + (kk + 1) * 64 + kb2) ^ sw;
      frag8 b0  = *(const frag8*)((const char*)wlds + (b0base + ko));
      frag8 b1  = *(const frag8*)((const char*)wlds + (b1base + ko));
      frag8 b02 = *(const frag8*)((const char*)wlds + (b0base + ko2));
      frag8 b12 = *(const frag8*)((const char*)wlds + (b1base + ko2));
      a0a = MFMA(hf[kk], b0, a0a);      a1a = MFMA(hf[kk], b1, a1a);
      a0b = MFMA(hf[kk + 1], b02, a0b); a1b = MFMA(hf[kk + 1], b12, a1b);
    }
  };

  compute_x(0);

  for (int t = 0; t < TS; ++t) {
    if (t > 0) h_part(t);            // h_{t=0} == 0: skip entirely

    const int tsrc = dir ? (TS - 1 - t) : t;
    f32x4 acc0 = a0a + a0b;   // tile0: gates i (lanes&8==0) / f (lanes&8)
    f32x4 acc1 = a1a + a1b;   // tile1: gates g / o

    ushort* hnext = hstate + ((size_t)(((t + 1) & 1) * 2 + dir) * BATCH) * HDIM;
    const size_t obase = ((size_t)tsrc * BATCH) * (2 * HDIM) + (size_t)dir * HDIM + hcol;
    const bool last = (t == TS - 1);
    const bool last_f = (dir == 0) && last;

    // ---- epilogue compute (no stores yet) ----
#pragma unroll
    for (int i = 0; i < 4; ++i) {
      float g0 = acc0[i] + bias0;
      float g1 = acc1[i] + bias1;
      float q0 = __shfl_xor(g0, 8);   // partner's gate (f when we hold i)
      float q1 = __shfl_xor(g1, 8);   // partner's gate (o when we hold g)
      if ((lane & 8) == 0) {
        float cn = sigf(q0) * creg[i] + sigf(g0) * tanh_fast(g1);
        creg[i] = cn;
        hvv[i] = sigf(q1) * tanh_fast(cn);
      }
    }

    // ---- h-state stores FIRST (the only stores the pre-flag wait covers) ----
    if (!last) {
#pragma unroll
      for (int i = 0; i < 4; ++i) {
        if ((lane & 8) == 0) {
          int brow = wv * 16 + (lane >> 4) * 4 + i;
          __hip_atomic_store(hnext + (size_t)brow * HDIM + hcol, f2b(hvv[i]),
                             __ATOMIC_RELAXED, __HIP_MEMORY_SCOPE_AGENT);
        }
      }
    }
    SB();
    // ---- out stores SECOND (acks drain lazily at the next h-wait) ----
#pragma unroll
    for (int i = 0; i < 4; ++i) {
      if ((lane & 8) == 0) {
        int brow = wv * 16 + (lane >> 4) * 4 + i;
        __builtin_nontemporal_store(hvv[i], out + obase + (size_t)brow * (2 * HDIM));
      }
    }
    if (last_f) {
#pragma unroll
      for (int i = 0; i < 4; ++i) {
        if ((lane & 8) == 0) {
          int brow = wv * 16 + (lane >> 4) * 4 + i;
          __builtin_nontemporal_store(hvv[i], out + HT_OFF + (size_t)brow * HDIM + hcol);
          __builtin_nontemporal_store(creg[i], out + CT_OFF + (size_t)brow * HDIM + hcol);
        }
      }
    }

    if (last) break;

    // ---- per-wave arrive: in-order vmcnt retirement -> vmcnt(4) guarantees
    //      the 4 h-state stores (oldest) reached the coherence point. Then one
    //      relaxed agent atomicAdd on the group counter (no release flush).
    asm volatile("s_waitcnt vmcnt(4)" ::: "memory");
    if (lane == 0)
      __hip_atomic_fetch_add(ctr, 1u, __ATOMIC_RELAXED, __HIP_MEMORY_SCOPE_AGENT);

    // ---- overlap counter propagation with next step's x-GEMM (h-independent)
    compute_x(t + 1);

    // ---- wait: all lanes poll the single group counter (one coalesced
    //      request per iteration) until 128 arrivals for step t+1.
    {
      const unsigned want = 128u * (unsigned)(t + 1);
      while (__hip_atomic_load(ctr, __ATOMIC_RELAXED, __HIP_MEMORY_SCOPE_AGENT) < want)
        __builtin_amdgcn_s_sleep(1);
    }
    __atomic_signal_fence(__ATOMIC_SEQ_CST);
    asm volatile("" ::: "memory");
  }
}

extern "C" void kernel_launch(void* const* d_in, const int* in_sizes, int n_in,
                              void* d_out, int out_size, void* d_ws, size_t ws_size,
                              hipStream_t stream) {
  const float* x    = (const float*)d_in[0];
  const float* Wih  = (const float*)d_in[1];
  const float* Whh  = (const float*)d_in[2];
  const float* b    = (const float*)d_in[3];
  const float* WihR = (const float*)d_in[4];
  const float* WhhR = (const float*)d_in[5];
  const float* bR   = (const float*)d_in[6];
  float* out = (float*)d_out;
  char* ws = (char*)d_ws;

  if (ws_size < WS_B_TOTAL) return;  // cannot run; surfaces as wrong-answer
  const bool modeA = (ws_size >= WS_A_TOTAL);

  ushort* wp  = (ushort*)(ws);
  ushort* xbf = (ushort*)(ws + WP_BYTES);
  size_t hs_off = modeA ? (WP_BYTES + XBF_BYTES) : WP_BYTES;
  ushort* hs = (ushort*)(ws + hs_off);
  unsigned* bar = (unsigned*)(ws + hs_off + HS_BYTES);

  // zero the counter region (monotonic within one launch; reset per launch)
  hipMemsetAsync(ws + hs_off + HS_BYTES, 0, BAR_BYTES, stream);

  // pack weights: 2 dirs * 128 p-tiles * 64 k-tiles
  wpackk<<<dim3(16384), dim3(256), 0, stream>>>(Wih, Whh, WihR, WhhR, wp);

  if (modeA) {
    xconv<<<dim3(16384), dim3(256), 0, stream>>>(x, xbf);  // 16384*256*8 == T*B*D
    lstm_scan<1><<<dim3(256), dim3(256), 0, stream>>>(xbf, x, wp, b, bR, hs, out, bar);
  } else {
    lstm_scan<0><<<dim3(256), dim3(256), 0, stream>>>(nullptr, x, wp, b, bR, hs, out, bar);
  }
}

// Round 19
// 4286.535 us; speedup vs baseline: 1.1469x; 1.0226x over previous
//
#include <hip/hip_runtime.h>
#include <hip/hip_bf16.h>

// Bidirectional LSTM, T=512 B=64 D=H=1024, fp32 in/out, bf16 MFMA compute.
// Persistent kernel: 256 WGs (1/CU), fwd=WG0..127, bwd=WG128..255.
// r18 structure (W bf16 LDS, asm sc1 32-deep h burst, ordered vmcnt(4)
// publish, NT out stores, aggregate-counter barrier) + SPLIT h drain:
// vmcnt(16) -> MFMA first half (overlaps second half's arrival) -> vmcnt(0)
// -> MFMA second half. Overlaps ~half the 128KB/CU transfer tail with compute.

#define TS    512
#define BATCH 64
#define DDIM  1024
#define HDIM  1024
#define KD    2048          // D + H
#define GD    4096          // 4H
#define OUT_HS ((size_t)TS * BATCH * 2 * HDIM)          // 67108864
#define HT_OFF OUT_HS
#define CT_OFF (OUT_HS + (size_t)BATCH * HDIM)

#define WP_BYTES   ((size_t)2 * GD * KD * 2)            // 32 MiB
#define XBF_BYTES  ((size_t)TS * BATCH * DDIM * 2)      // 64 MiB
#define HS_BYTES   ((size_t)2 * 2 * BATCH * HDIM * 2)   // 512 KiB
#define BAR_BYTES  ((size_t)4096)                       // 8 counters, 256B apart
#define WS_A_TOTAL (WP_BYTES + XBF_BYTES + HS_BYTES + BAR_BYTES)
#define WS_B_TOTAL (WP_BYTES + HS_BYTES + BAR_BYTES)

typedef __attribute__((ext_vector_type(8))) short frag8;
typedef __attribute__((ext_vector_type(4))) float f32x4;
typedef unsigned long long u64;

__device__ __forceinline__ ushort f2b(float f) {
  union { float f; unsigned u; } v; v.f = f;
  unsigned r = v.u + 0x7FFFu + ((v.u >> 16) & 1u);   // RNE
  return (ushort)(r >> 16);
}
__device__ __forceinline__ float sigf(float x) { return 1.0f / (1.0f + __expf(-x)); }
__device__ __forceinline__ float tanh_fast(float x) {
  x = fminf(15.0f, fmaxf(-15.0f, x));
  float e = __expf(2.0f * x);
  return (e - 1.0f) / (e + 1.0f);
}

// ---------------- pack kernels ----------------

__global__ void xconv(const float* __restrict__ x, ushort* __restrict__ o) {
  size_t i = ((size_t)blockIdx.x * 256 + threadIdx.x) * 8;
  float4 a = *(const float4*)(x + i);
  float4 b = *(const float4*)(x + i + 4);
  union { ushort s[8]; uint4 v; } r;
  r.s[0] = f2b(a.x); r.s[1] = f2b(a.y); r.s[2] = f2b(a.z); r.s[3] = f2b(a.w);
  r.s[4] = f2b(b.x); r.s[5] = f2b(b.y); r.s[6] = f2b(b.z); r.s[7] = f2b(b.w);
  *(uint4*)(o + i) = r.v;
}

// Build Wpack[dir][p][k] bf16 (k-major), p = wq*32 + gate*8 + jj maps to
// source column n = gate*1024 + wq*8 + jj; rows k<1024 from Wih, else Whh.
__global__ void wpackk(const float* __restrict__ Wih,  const float* __restrict__ Whh,
                       const float* __restrict__ WihR, const float* __restrict__ WhhR,
                       ushort* __restrict__ wp) {
  __shared__ ushort tile[32][36];   // [k_local][p_local]
  int bid = blockIdx.x;
  int kt  = bid & 63;
  int pt  = (bid >> 6) & 127;
  int dir = bid >> 13;
  const float* Wi = dir ? WihR : Wih;
  const float* Wh = dir ? WhhR : Whh;
  int t  = threadIdx.x;
  int kl = t >> 3;
  int g  = (t >> 1) & 3;
  int q  = t & 1;
  int k  = kt * 32 + kl;
  const float* srow = (k < 1024) ? (Wi + (size_t)k * GD) : (Wh + (size_t)(k - 1024) * GD);
  float4 v = *(const float4*)(srow + g * 1024 + pt * 8 + q * 4);
  int pl = g * 8 + q * 4;
  tile[kl][pl + 0] = f2b(v.x); tile[kl][pl + 1] = f2b(v.y);
  tile[kl][pl + 2] = f2b(v.z); tile[kl][pl + 3] = f2b(v.w);
  __syncthreads();
  int po = t >> 3;
  int kc = t & 7;
  ushort* dst = wp + ((size_t)dir * GD + pt * 32 + po) * KD + kt * 32 + kc * 4;
  ushort4 ov;
  ov.x = tile[kc * 4 + 0][po]; ov.y = tile[kc * 4 + 1][po];
  ov.z = tile[kc * 4 + 2][po]; ov.w = tile[kc * 4 + 3][po];
  *(ushort4*)dst = ov;
}

#define MFMA(a, b, c) __builtin_amdgcn_mfma_f32_16x16x32_bf16((a), (b), (c), 0, 0, 0)
#define SB() __builtin_amdgcn_sched_barrier(0)

// ---------------- persistent scan kernel ----------------
// Counter layout in `bar` (zeroed per launch): group g = dir*4 + wv owns the
// counter at bar[g*64] (256B apart -> distinct lines). Each of the group's
// 128 producer waves adds +1 per step AFTER its h-stores drained (vmcnt(4));
// consumers wait until ctr >= 128*(t+1). Monotonic within a launch.
template <int MODEA>
__global__ __launch_bounds__(256, 1)
void lstm_scan(const ushort* __restrict__ xbf, const float* __restrict__ xf,
               const ushort* __restrict__ wpack,
               const float* __restrict__ bfwd, const float* __restrict__ bbwd,
               ushort* hstate, float* __restrict__ out, unsigned* bar) {
  __shared__ ushort wlds[32 * KD];   // 128 KiB: this WG's 32 packed cols x 2048 K, swizzled

  const int tid  = threadIdx.x;
  const int lane = tid & 63;
  const int wv   = tid >> 6;         // wave 0..3 -> rows wv*16..
  const int wg   = blockIdx.x;
  const int dir  = wg >> 7;          // 0 fwd, 1 bwd
  const int wq   = wg & 127;         // owns h-cols [wq*8, wq*8+8)
  unsigned* ctr  = bar + (dir * 4 + wv) * 64;   // this wave's group counter

  // stage W slice into LDS (XOR swizzle: byte ^= (p&7)<<4)
  {
    const ushort* src = wpack + ((size_t)dir * GD + wq * 32) * KD;
#pragma unroll
    for (int it = 0; it < 32; ++it) {
      int m  = it * 256 + tid;
      int p  = m >> 8;
      int kc = m & 255;
      uint4 v = *(const uint4*)(src + (size_t)p * KD + kc * 8);
      int off = p * 4096 + ((kc * 16) ^ ((p & 7) << 4));
      *(uint4*)((char*)wlds + off) = v;
    }
  }
  __syncthreads();   // only sync: W staging complete; LDS read-only afterwards

  const int lm   = lane & 15;
  const int jj   = lane & 7;
  const int kb   = (lane >> 4) * 8;  // A-frag k sub-block (elements)
  const int kb2  = kb * 2;           // bytes
  const int arow = wv * 16 + lm;     // A row this lane reads
  const int hcol = wq * 8 + jj;
  const int sw   = jj << 4;          // == (p&7)<<4 for both tiles
  const int b0base = lm * 4096;
  const int b1base = (16 + lm) * 4096;

  const float* bsrc = dir ? bbwd : bfwd;
  const float bias0 = bsrc[(lm >> 3) * HDIM + hcol];        // gate 0/1 (i,f)
  const float bias1 = bsrc[(2 + (lm >> 3)) * HDIM + hcol];  // gate 2/3 (g,o)

  float creg[4] = {0.f, 0.f, 0.f, 0.f};
  float hvv[4];
  f32x4 a0a, a0b, a1a, a1b;

  // ---- x contribution for timestep tt (k in [0,1024)); resets accumulators ----
  auto compute_x = [&](int tt) {
    const int tsrc = dir ? (TS - 1 - tt) : tt;
    a0a = (f32x4){0.f,0.f,0.f,0.f}; a0b = (f32x4){0.f,0.f,0.f,0.f};
    a1a = (f32x4){0.f,0.f,0.f,0.f}; a1b = (f32x4){0.f,0.f,0.f,0.f};
    if (MODEA) {
      const ushort* xs = xbf + ((size_t)tsrc * BATCH + arow) * DDIM + kb;
#pragma unroll 8
      for (int kk = 0; kk < 32; kk += 2) {
        frag8 a  = *(const frag8*)(xs + kk * 32);
        frag8 a2 = *(const frag8*)(xs + (kk + 1) * 32);
        int ko  = (kk * 64 + kb2) ^ sw;
        int ko2 = ((kk + 1) * 64 + kb2) ^ sw;
        frag8 b0  = *(const frag8*)((const char*)wlds + (b0base + ko));
        frag8 b1  = *(const frag8*)((const char*)wlds + (b1base + ko));
        frag8 b02 = *(const frag8*)((const char*)wlds + (b0base + ko2));
        frag8 b12 = *(const frag8*)((const char*)wlds + (b1base + ko2));
        a0a = MFMA(a, b0, a0a);  a1a = MFMA(a, b1, a1a);
        a0b = MFMA(a2, b02, a0b); a1b = MFMA(a2, b12, a1b);
      }
    } else {
      const float* xs = xf + ((size_t)tsrc * BATCH + arow) * DDIM + kb;
#pragma unroll 4
      for (int kk = 0; kk < 32; ++kk) {
        float4 f0 = *(const float4*)(xs + kk * 32);
        float4 f1 = *(const float4*)(xs + kk * 32 + 4);
        union { ushort s[8]; frag8 fr; } ua;
        ua.s[0] = f2b(f0.x); ua.s[1] = f2b(f0.y); ua.s[2] = f2b(f0.z); ua.s[3] = f2b(f0.w);
        ua.s[4] = f2b(f1.x); ua.s[5] = f2b(f1.y); ua.s[6] = f2b(f1.z); ua.s[7] = f2b(f1.w);
        int ko = (kk * 64 + kb2) ^ sw;
        frag8 b0 = *(const frag8*)((const char*)wlds + (b0base + ko));
        frag8 b1 = *(const frag8*)((const char*)wlds + (b1base + ko));
        if (kk & 1) { a0b = MFMA(ua.fr, b0, a0b); a1b = MFMA(ua.fr, b1, a1b); }
        else        { a0a = MFMA(ua.fr, b0, a0a); a1a = MFMA(ua.fr, b1, a1a); }
      }
    }
  };

  // ---- h contribution for timestep t (k in [1024,2048)) ----
  // Inline-asm FORCED 32-deep sc1 load burst with SPLIT drain: vmcnt(16)
  // releases the first half into MFMAs while the second half is in flight;
  // vmcnt(0) before the second half's MFMAs. sched_barrier per rule #18.
  // (The poll preceding this call drained vmcnt to 0, so the counts are
  // exactly the h loads.)
  auto h_part = [&](int t) {
    const ushort* hsrd = hstate + (((size_t)(t & 1) * 2 + dir) * BATCH + arow) * HDIM + kb;
    frag8 hf[32];
#pragma unroll
    for (int kk = 0; kk < 32; ++kk)
      asm volatile("global_load_dwordx4 %0, %1, off offset:%2 sc1"
                   : "=v"(hf[kk]) : "v"(hsrd), "i"(kk * 64) : "memory");
    asm volatile("s_waitcnt vmcnt(16)" ::: "memory");   // first 16 arrived
    SB();
#pragma unroll
    for (int kk = 0; kk < 16; kk += 2) {
      int ko  = (2048 + kk * 64 + kb2) ^ sw;
      int ko2 = (2048 + (kk + 1) * 64 + kb2) ^ sw;
      frag8 b0  = *(const frag8*)((const char*)wlds + (b0base + ko));
      frag8 b1  = *(const frag8*)((const char*)wlds + (b1base + ko));
      frag8 b02 = *(const frag8*)((const char*)wlds + (b0base + ko2));
      frag8 b12 = *(const frag8*)((const char*)wlds + (b1base + ko2));
      a0a = MFMA(hf[kk], b0, a0a);      a1a = MFMA(hf[kk], b1, a1a);
      a0b = MFMA(hf[kk + 1], b02, a0b); a1b = MFMA(hf[kk + 1], b12, a1b);
    }
    asm volatile("s_waitcnt vmcnt(0)" ::: "memory");    // rest arrived
    SB();
#pragma unroll
    for (int kk = 16; kk < 32; kk += 2) {
      int ko  = (2048 + kk * 64 + kb2) ^ sw;
      int ko2 = (2048 + (kk + 1) * 64 + kb2) ^ sw;
      frag8 b0  = *(const frag8*)((const char*)wlds + (b0base + ko));
      frag8 b1  = *(const frag8*)((const char*)wlds + (b1base + ko));
      frag8 b02 = *(const frag8*)((const char*)wlds + (b0base + ko2));
      frag8 b12 = *(const frag8*)((const char*)wlds + (b1base + ko2));
      a0a = MFMA(hf[kk], b0, a0a);      a1a = MFMA(hf[kk], b1, a1a);
      a0b = MFMA(hf[kk + 1], b02, a0b); a1b = MFMA(hf[kk + 1], b12, a1b);
    }
  };

  compute_x(0);

  for (int t = 0; t < TS; ++t) {
    if (t > 0) h_part(t);            // h_{t=0} == 0: skip entirely

    const int tsrc = dir ? (TS - 1 - t) : t;
    f32x4 acc0 = a0a + a0b;   // tile0: gates i (lanes&8==0) / f (lanes&8)
    f32x4 acc1 = a1a + a1b;   // tile1: gates g / o

    ushort* hnext = hstate + ((size_t)(((t + 1) & 1) * 2 + dir) * BATCH) * HDIM;
    const size_t obase = ((size_t)tsrc * BATCH) * (2 * HDIM) + (size_t)dir * HDIM + hcol;
    const bool last = (t == TS - 1);
    const bool last_f = (dir == 0) && last;

    // ---- epilogue compute (no stores yet) ----
#pragma unroll
    for (int i = 0; i < 4; ++i) {
      float g0 = acc0[i] + bias0;
      float g1 = acc1[i] + bias1;
      float q0 = __shfl_xor(g0, 8);   // partner's gate (f when we hold i)
      float q1 = __shfl_xor(g1, 8);   // partner's gate (o when we hold g)
      if ((lane & 8) == 0) {
        float cn = sigf(q0) * creg[i] + sigf(g0) * tanh_fast(g1);
        creg[i] = cn;
        hvv[i] = sigf(q1) * tanh_fast(cn);
      }
    }

    // ---- h-state stores FIRST (the only stores the pre-flag wait covers) ----
    if (!last) {
#pragma unroll
      for (int i = 0; i < 4; ++i) {
        if ((lane & 8) == 0) {
          int brow = wv * 16 + (lane >> 4) * 4 + i;
          __hip_atomic_store(hnext + (size_t)brow * HDIM + hcol, f2b(hvv[i]),
                             __ATOMIC_RELAXED, __HIP_MEMORY_SCOPE_AGENT);
        }
      }
    }
    SB();
    // ---- out stores SECOND (acks drain lazily at the next h-wait) ----
#pragma unroll
    for (int i = 0; i < 4; ++i) {
      if ((lane & 8) == 0) {
        int brow = wv * 16 + (lane >> 4) * 4 + i;
        __builtin_nontemporal_store(hvv[i], out + obase + (size_t)brow * (2 * HDIM));
      }
    }
    if (last_f) {
#pragma unroll
      for (int i = 0; i < 4; ++i) {
        if ((lane & 8) == 0) {
          int brow = wv * 16 + (lane >> 4) * 4 + i;
          __builtin_nontemporal_store(hvv[i], out + HT_OFF + (size_t)brow * HDIM + hcol);
          __builtin_nontemporal_store(creg[i], out + CT_OFF + (size_t)brow * HDIM + hcol);
        }
      }
    }

    if (last) break;

    // ---- per-wave arrive: in-order vmcnt retirement -> vmcnt(4) guarantees
    //      the 4 h-state stores (oldest) reached the coherence point. Then one
    //      relaxed agent atomicAdd on the group counter (no release flush).
    asm volatile("s_waitcnt vmcnt(4)" ::: "memory");
    if (lane == 0)
      __hip_atomic_fetch_add(ctr, 1u, __ATOMIC_RELAXED, __HIP_MEMORY_SCOPE_AGENT);

    // ---- overlap counter propagation with next step's x-GEMM (h-independent)
    compute_x(t + 1);

    // ---- wait: all lanes poll the single group counter (one coalesced
    //      request per iteration) until 128 arrivals for step t+1.
    {
      const unsigned want = 128u * (unsigned)(t + 1);
      while (__hip_atomic_load(ctr, __ATOMIC_RELAXED, __HIP_MEMORY_SCOPE_AGENT) < want)
        __builtin_amdgcn_s_sleep(1);
    }
    __atomic_signal_fence(__ATOMIC_SEQ_CST);
    asm volatile("" ::: "memory");
  }
}

extern "C" void kernel_launch(void* const* d_in, const int* in_sizes, int n_in,
                              void* d_out, int out_size, void* d_ws, size_t ws_size,
                              hipStream_t stream) {
  const float* x    = (const float*)d_in[0];
  const float* Wih  = (const float*)d_in[1];
  const float* Whh  = (const float*)d_in[2];
  const float* b    = (const float*)d_in[3];
  const float* WihR = (const float*)d_in[4];
  const float* WhhR = (const float*)d_in[5];
  const float* bR   = (const float*)d_in[6];
  float* out = (float*)d_out;
  char* ws = (char*)d_ws;

  if (ws_size < WS_B_TOTAL) return;  // cannot run; surfaces as wrong-answer
  const bool modeA = (ws_size >= WS_A_TOTAL);

  ushort* wp  = (ushort*)(ws);
  ushort* xbf = (ushort*)(ws + WP_BYTES);
  size_t hs_off = modeA ? (WP_BYTES + XBF_BYTES) : WP_BYTES;
  ushort* hs = (ushort*)(ws + hs_off);
  unsigned* bar = (unsigned*)(ws + hs_off + HS_BYTES);

  // zero the counter region (monotonic within one launch; reset per launch)
  hipMemsetAsync(ws + hs_off + HS_BYTES, 0, BAR_BYTES, stream);

  // pack weights: 2 dirs * 128 p-tiles * 64 k-tiles
  wpackk<<<dim3(16384), dim3(256), 0, stream>>>(Wih, Whh, WihR, WhhR, wp);

  if (modeA) {
    xconv<<<dim3(16384), dim3(256), 0, stream>>>(x, xbf);  // 16384*256*8 == T*B*D
    lstm_scan<1><<<dim3(256), dim3(256), 0, stream>>>(xbf, x, wp, b, bR, hs, out, bar);
  } else {
    lstm_scan<0><<<dim3(256), dim3(256), 0, stream>>>(nullptr, x, wp, b, bR, hs, out, bar);
  }
}

// Round 20
// 4269.168 us; speedup vs baseline: 1.1516x; 1.0041x over previous
//
#include <hip/hip_runtime.h>
#include <hip/hip_bf16.h>

// Bidirectional LSTM, T=512 B=64 D=H=1024, fp32 in/out, bf16 MFMA compute.
// Persistent kernel: 256 WGs (1/CU), fwd=WG0..127, bwd=WG128..255.
// r19 structure (W bf16 LDS, asm sc1 32-deep h burst, ordered vmcnt(4)
// publish, NT out stores, aggregate-counter barrier) + 4-WAY split h drain:
// vmcnt(24)/(16)/(8)/(0), each releasing 8 loads into 16 MFMAs while later
// chunks fly — starts compute one chunk earlier, hides 3 MFMA sections.

#define TS    512
#define BATCH 64
#define DDIM  1024
#define HDIM  1024
#define KD    2048          // D + H
#define GD    4096          // 4H
#define OUT_HS ((size_t)TS * BATCH * 2 * HDIM)          // 67108864
#define HT_OFF OUT_HS
#define CT_OFF (OUT_HS + (size_t)BATCH * HDIM)

#define WP_BYTES   ((size_t)2 * GD * KD * 2)            // 32 MiB
#define XBF_BYTES  ((size_t)TS * BATCH * DDIM * 2)      // 64 MiB
#define HS_BYTES   ((size_t)2 * 2 * BATCH * HDIM * 2)   // 512 KiB
#define BAR_BYTES  ((size_t)4096)                       // 8 counters, 256B apart
#define WS_A_TOTAL (WP_BYTES + XBF_BYTES + HS_BYTES + BAR_BYTES)
#define WS_B_TOTAL (WP_BYTES + HS_BYTES + BAR_BYTES)

typedef __attribute__((ext_vector_type(8))) short frag8;
typedef __attribute__((ext_vector_type(4))) float f32x4;
typedef unsigned long long u64;

__device__ __forceinline__ ushort f2b(float f) {
  union { float f; unsigned u; } v; v.f = f;
  unsigned r = v.u + 0x7FFFu + ((v.u >> 16) & 1u);   // RNE
  return (ushort)(r >> 16);
}
__device__ __forceinline__ float sigf(float x) { return 1.0f / (1.0f + __expf(-x)); }
__device__ __forceinline__ float tanh_fast(float x) {
  x = fminf(15.0f, fmaxf(-15.0f, x));
  float e = __expf(2.0f * x);
  return (e - 1.0f) / (e + 1.0f);
}

// ---------------- pack kernels ----------------

__global__ void xconv(const float* __restrict__ x, ushort* __restrict__ o) {
  size_t i = ((size_t)blockIdx.x * 256 + threadIdx.x) * 8;
  float4 a = *(const float4*)(x + i);
  float4 b = *(const float4*)(x + i + 4);
  union { ushort s[8]; uint4 v; } r;
  r.s[0] = f2b(a.x); r.s[1] = f2b(a.y); r.s[2] = f2b(a.z); r.s[3] = f2b(a.w);
  r.s[4] = f2b(b.x); r.s[5] = f2b(b.y); r.s[6] = f2b(b.z); r.s[7] = f2b(b.w);
  *(uint4*)(o + i) = r.v;
}

// Build Wpack[dir][p][k] bf16 (k-major), p = wq*32 + gate*8 + jj maps to
// source column n = gate*1024 + wq*8 + jj; rows k<1024 from Wih, else Whh.
__global__ void wpackk(const float* __restrict__ Wih,  const float* __restrict__ Whh,
                       const float* __restrict__ WihR, const float* __restrict__ WhhR,
                       ushort* __restrict__ wp) {
  __shared__ ushort tile[32][36];   // [k_local][p_local]
  int bid = blockIdx.x;
  int kt  = bid & 63;
  int pt  = (bid >> 6) & 127;
  int dir = bid >> 13;
  const float* Wi = dir ? WihR : Wih;
  const float* Wh = dir ? WhhR : Whh;
  int t  = threadIdx.x;
  int kl = t >> 3;
  int g  = (t >> 1) & 3;
  int q  = t & 1;
  int k  = kt * 32 + kl;
  const float* srow = (k < 1024) ? (Wi + (size_t)k * GD) : (Wh + (size_t)(k - 1024) * GD);
  float4 v = *(const float4*)(srow + g * 1024 + pt * 8 + q * 4);
  int pl = g * 8 + q * 4;
  tile[kl][pl + 0] = f2b(v.x); tile[kl][pl + 1] = f2b(v.y);
  tile[kl][pl + 2] = f2b(v.z); tile[kl][pl + 3] = f2b(v.w);
  __syncthreads();
  int po = t >> 3;
  int kc = t & 7;
  ushort* dst = wp + ((size_t)dir * GD + pt * 32 + po) * KD + kt * 32 + kc * 4;
  ushort4 ov;
  ov.x = tile[kc * 4 + 0][po]; ov.y = tile[kc * 4 + 1][po];
  ov.z = tile[kc * 4 + 2][po]; ov.w = tile[kc * 4 + 3][po];
  *(ushort4*)dst = ov;
}

#define MFMA(a, b, c) __builtin_amdgcn_mfma_f32_16x16x32_bf16((a), (b), (c), 0, 0, 0)
#define SB() __builtin_amdgcn_sched_barrier(0)

// ---------------- persistent scan kernel ----------------
// Counter layout in `bar` (zeroed per launch): group g = dir*4 + wv owns the
// counter at bar[g*64] (256B apart -> distinct lines). Each of the group's
// 128 producer waves adds +1 per step AFTER its h-stores drained (vmcnt(4));
// consumers wait until ctr >= 128*(t+1). Monotonic within a launch.
template <int MODEA>
__global__ __launch_bounds__(256, 1)
void lstm_scan(const ushort* __restrict__ xbf, const float* __restrict__ xf,
               const ushort* __restrict__ wpack,
               const float* __restrict__ bfwd, const float* __restrict__ bbwd,
               ushort* hstate, float* __restrict__ out, unsigned* bar) {
  __shared__ ushort wlds[32 * KD];   // 128 KiB: this WG's 32 packed cols x 2048 K, swizzled

  const int tid  = threadIdx.x;
  const int lane = tid & 63;
  const int wv   = tid >> 6;         // wave 0..3 -> rows wv*16..
  const int wg   = blockIdx.x;
  const int dir  = wg >> 7;          // 0 fwd, 1 bwd
  const int wq   = wg & 127;         // owns h-cols [wq*8, wq*8+8)
  unsigned* ctr  = bar + (dir * 4 + wv) * 64;   // this wave's group counter

  // stage W slice into LDS (XOR swizzle: byte ^= (p&7)<<4)
  {
    const ushort* src = wpack + ((size_t)dir * GD + wq * 32) * KD;
#pragma unroll
    for (int it = 0; it < 32; ++it) {
      int m  = it * 256 + tid;
      int p  = m >> 8;
      int kc = m & 255;
      uint4 v = *(const uint4*)(src + (size_t)p * KD + kc * 8);
      int off = p * 4096 + ((kc * 16) ^ ((p & 7) << 4));
      *(uint4*)((char*)wlds + off) = v;
    }
  }
  __syncthreads();   // only sync: W staging complete; LDS read-only afterwards

  const int lm   = lane & 15;
  const int jj   = lane & 7;
  const int kb   = (lane >> 4) * 8;  // A-frag k sub-block (elements)
  const int kb2  = kb * 2;           // bytes
  const int arow = wv * 16 + lm;     // A row this lane reads
  const int hcol = wq * 8 + jj;
  const int sw   = jj << 4;          // == (p&7)<<4 for both tiles
  const int b0base = lm * 4096;
  const int b1base = (16 + lm) * 4096;

  const float* bsrc = dir ? bbwd : bfwd;
  const float bias0 = bsrc[(lm >> 3) * HDIM + hcol];        // gate 0/1 (i,f)
  const float bias1 = bsrc[(2 + (lm >> 3)) * HDIM + hcol];  // gate 2/3 (g,o)

  float creg[4] = {0.f, 0.f, 0.f, 0.f};
  float hvv[4];
  f32x4 a0a, a0b, a1a, a1b;

  // ---- x contribution for timestep tt (k in [0,1024)); resets accumulators ----
  auto compute_x = [&](int tt) {
    const int tsrc = dir ? (TS - 1 - tt) : tt;
    a0a = (f32x4){0.f,0.f,0.f,0.f}; a0b = (f32x4){0.f,0.f,0.f,0.f};
    a1a = (f32x4){0.f,0.f,0.f,0.f}; a1b = (f32x4){0.f,0.f,0.f,0.f};
    if (MODEA) {
      const ushort* xs = xbf + ((size_t)tsrc * BATCH + arow) * DDIM + kb;
#pragma unroll 8
      for (int kk = 0; kk < 32; kk += 2) {
        frag8 a  = *(const frag8*)(xs + kk * 32);
        frag8 a2 = *(const frag8*)(xs + (kk + 1) * 32);
        int ko  = (kk * 64 + kb2) ^ sw;
        int ko2 = ((kk + 1) * 64 + kb2) ^ sw;
        frag8 b0  = *(const frag8*)((const char*)wlds + (b0base + ko));
        frag8 b1  = *(const frag8*)((const char*)wlds + (b1base + ko));
        frag8 b02 = *(const frag8*)((const char*)wlds + (b0base + ko2));
        frag8 b12 = *(const frag8*)((const char*)wlds + (b1base + ko2));
        a0a = MFMA(a, b0, a0a);  a1a = MFMA(a, b1, a1a);
        a0b = MFMA(a2, b02, a0b); a1b = MFMA(a2, b12, a1b);
      }
    } else {
      const float* xs = xf + ((size_t)tsrc * BATCH + arow) * DDIM + kb;
#pragma unroll 4
      for (int kk = 0; kk < 32; ++kk) {
        float4 f0 = *(const float4*)(xs + kk * 32);
        float4 f1 = *(const float4*)(xs + kk * 32 + 4);
        union { ushort s[8]; frag8 fr; } ua;
        ua.s[0] = f2b(f0.x); ua.s[1] = f2b(f0.y); ua.s[2] = f2b(f0.z); ua.s[3] = f2b(f0.w);
        ua.s[4] = f2b(f1.x); ua.s[5] = f2b(f1.y); ua.s[6] = f2b(f1.z); ua.s[7] = f2b(f1.w);
        int ko = (kk * 64 + kb2) ^ sw;
        frag8 b0 = *(const frag8*)((const char*)wlds + (b0base + ko));
        frag8 b1 = *(const frag8*)((const char*)wlds + (b1base + ko));
        if (kk & 1) { a0b = MFMA(ua.fr, b0, a0b); a1b = MFMA(ua.fr, b1, a1b); }
        else        { a0a = MFMA(ua.fr, b0, a0a); a1a = MFMA(ua.fr, b1, a1a); }
      }
    }
  };

  // ---- h contribution for timestep t (k in [1024,2048)) ----
  // Inline-asm FORCED 32-deep sc1 load burst with 4-WAY split drain:
  // vmcnt(24)/(16)/(8)/(0), each releasing 8 loads into 16 MFMAs while later
  // chunks fly. sched_barrier per rule #18. (The poll preceding this call
  // drained vmcnt to 0, so the counts are exactly the h loads.)
  auto h_part = [&](int t) {
    const ushort* hsrd = hstate + (((size_t)(t & 1) * 2 + dir) * BATCH + arow) * HDIM + kb;
    frag8 hf[32];
#pragma unroll
    for (int kk = 0; kk < 32; ++kk)
      asm volatile("global_load_dwordx4 %0, %1, off offset:%2 sc1"
                   : "=v"(hf[kk]) : "v"(hsrd), "i"(kk * 64) : "memory");
#pragma unroll
    for (int c = 0; c < 4; ++c) {
      if (c == 0)      asm volatile("s_waitcnt vmcnt(24)" ::: "memory");
      else if (c == 1) asm volatile("s_waitcnt vmcnt(16)" ::: "memory");
      else if (c == 2) asm volatile("s_waitcnt vmcnt(8)"  ::: "memory");
      else             asm volatile("s_waitcnt vmcnt(0)"  ::: "memory");
      SB();
#pragma unroll
      for (int kk = c * 8; kk < c * 8 + 8; kk += 2) {
        int ko  = (2048 + kk * 64 + kb2) ^ sw;
        int ko2 = (2048 + (kk + 1) * 64 + kb2) ^ sw;
        frag8 b0  = *(const frag8*)((const char*)wlds + (b0base + ko));
        frag8 b1  = *(const frag8*)((const char*)wlds + (b1base + ko));
        frag8 b02 = *(const frag8*)((const char*)wlds + (b0base + ko2));
        frag8 b12 = *(const frag8*)((const char*)wlds + (b1base + ko2));
        a0a = MFMA(hf[kk], b0, a0a);      a1a = MFMA(hf[kk], b1, a1a);
        a0b = MFMA(hf[kk + 1], b02, a0b); a1b = MFMA(hf[kk + 1], b12, a1b);
      }
    }
  };

  compute_x(0);

  for (int t = 0; t < TS; ++t) {
    if (t > 0) h_part(t);            // h_{t=0} == 0: skip entirely

    const int tsrc = dir ? (TS - 1 - t) : t;
    f32x4 acc0 = a0a + a0b;   // tile0: gates i (lanes&8==0) / f (lanes&8)
    f32x4 acc1 = a1a + a1b;   // tile1: gates g / o

    ushort* hnext = hstate + ((size_t)(((t + 1) & 1) * 2 + dir) * BATCH) * HDIM;
    const size_t obase = ((size_t)tsrc * BATCH) * (2 * HDIM) + (size_t)dir * HDIM + hcol;
    const bool last = (t == TS - 1);
    const bool last_f = (dir == 0) && last;

    // ---- epilogue compute (no stores yet) ----
#pragma unroll
    for (int i = 0; i < 4; ++i) {
      float g0 = acc0[i] + bias0;
      float g1 = acc1[i] + bias1;
      float q0 = __shfl_xor(g0, 8);   // partner's gate (f when we hold i)
      float q1 = __shfl_xor(g1, 8);   // partner's gate (o when we hold g)
      if ((lane & 8) == 0) {
        float cn = sigf(q0) * creg[i] + sigf(g0) * tanh_fast(g1);
        creg[i] = cn;
        hvv[i] = sigf(q1) * tanh_fast(cn);
      }
    }

    // ---- h-state stores FIRST (the only stores the pre-flag wait covers) ----
    if (!last) {
#pragma unroll
      for (int i = 0; i < 4; ++i) {
        if ((lane & 8) == 0) {
          int brow = wv * 16 + (lane >> 4) * 4 + i;
          __hip_atomic_store(hnext + (size_t)brow * HDIM + hcol, f2b(hvv[i]),
                             __ATOMIC_RELAXED, __HIP_MEMORY_SCOPE_AGENT);
        }
      }
    }
    SB();
    // ---- out stores SECOND (acks drain lazily at the next h-wait) ----
#pragma unroll
    for (int i = 0; i < 4; ++i) {
      if ((lane & 8) == 0) {
        int brow = wv * 16 + (lane >> 4) * 4 + i;
        __builtin_nontemporal_store(hvv[i], out + obase + (size_t)brow * (2 * HDIM));
      }
    }
    if (last_f) {
#pragma unroll
      for (int i = 0; i < 4; ++i) {
        if ((lane & 8) == 0) {
          int brow = wv * 16 + (lane >> 4) * 4 + i;
          __builtin_nontemporal_store(hvv[i], out + HT_OFF + (size_t)brow * HDIM + hcol);
          __builtin_nontemporal_store(creg[i], out + CT_OFF + (size_t)brow * HDIM + hcol);
        }
      }
    }

    if (last) break;

    // ---- per-wave arrive: in-order vmcnt retirement -> vmcnt(4) guarantees
    //      the 4 h-state stores (oldest) reached the coherence point. Then one
    //      relaxed agent atomicAdd on the group counter (no release flush).
    asm volatile("s_waitcnt vmcnt(4)" ::: "memory");
    if (lane == 0)
      __hip_atomic_fetch_add(ctr, 1u, __ATOMIC_RELAXED, __HIP_MEMORY_SCOPE_AGENT);

    // ---- overlap counter propagation with next step's x-GEMM (h-independent)
    compute_x(t + 1);

    // ---- wait: all lanes poll the single group counter (one coalesced
    //      request per iteration) until 128 arrivals for step t+1.
    {
      const unsigned want = 128u * (unsigned)(t + 1);
      while (__hip_atomic_load(ctr, __ATOMIC_RELAXED, __HIP_MEMORY_SCOPE_AGENT) < want)
        __builtin_amdgcn_s_sleep(1);
    }
    __atomic_signal_fence(__ATOMIC_SEQ_CST);
    asm volatile("" ::: "memory");
  }
}

extern "C" void kernel_launch(void* const* d_in, const int* in_sizes, int n_in,
                              void* d_out, int out_size, void* d_ws, size_t ws_size,
                              hipStream_t stream) {
  const float* x    = (const float*)d_in[0];
  const float* Wih  = (const float*)d_in[1];
  const float* Whh  = (const float*)d_in[2];
  const float* b    = (const float*)d_in[3];
  const float* WihR = (const float*)d_in[4];
  const float* WhhR = (const float*)d_in[5];
  const float* bR   = (const float*)d_in[6];
  float* out = (float*)d_out;
  char* ws = (char*)d_ws;

  if (ws_size < WS_B_TOTAL) return;  // cannot run; surfaces as wrong-answer
  const bool modeA = (ws_size >= WS_A_TOTAL);

  ushort* wp  = (ushort*)(ws);
  ushort* xbf = (ushort*)(ws + WP_BYTES);
  size_t hs_off = modeA ? (WP_BYTES + XBF_BYTES) : WP_BYTES;
  ushort* hs = (ushort*)(ws + hs_off);
  unsigned* bar = (unsigned*)(ws + hs_off + HS_BYTES);

  // zero the counter region (monotonic within one launch; reset per launch)
  hipMemsetAsync(ws + hs_off + HS_BYTES, 0, BAR_BYTES, stream);

  // pack weights: 2 dirs * 128 p-tiles * 64 k-tiles
  wpackk<<<dim3(16384), dim3(256), 0, stream>>>(Wih, Whh, WihR, WhhR, wp);

  if (modeA) {
    xconv<<<dim3(16384), dim3(256), 0, stream>>>(x, xbf);  // 16384*256*8 == T*B*D
    lstm_scan<1><<<dim3(256), dim3(256), 0, stream>>>(xbf, x, wp, b, bR, hs, out, bar);
  } else {
    lstm_scan<0><<<dim3(256), dim3(256), 0, stream>>>(nullptr, x, wp, b, bR, hs, out, bar);
  }
}